// Round 1
// baseline (9482.873 us; speedup 1.0000x reference)
//
#include <hip/hip_runtime.h>
#include <hip/hip_bf16.h>

// Problem constants
#define BATCH 1024
#define SEQ   350
#define LAT   512
#define VOC   41
#define H0D   512
#define H1D   256
#define H2D   128
#define H3D   32
#define G1    768   // 3*H1D
#define G2    384   // 3*H2D
#define G3    96    // 3*H3D
#define SOS   1

// ws layout (floats) — UNCHANGED from previous passing version
#define O_HH0   0         // wt_hh0 [256][768]
#define O_IH1   196608    // wt_ih1 [256][384]
#define O_HH1   294912    // wt_hh1 [128][384]
#define O_IH2   344064    // wt_ih2 [128][96]
#define O_HH2   356352    // wt_hh2 [32][96]
#define O_PROJ  359424    // wt_proj [32][41]
#define O_TAB   360736    // gi0 table [41][768]
#define WS_FLOATS 392224

#define RT 4    // batch rows per block
#define NT 512  // threads per block (8 waves)

__global__ void setup_kernel(const float* __restrict__ Whh0, const float* __restrict__ Wih1,
                             const float* __restrict__ Whh1, const float* __restrict__ Wih2,
                             const float* __restrict__ Whh2, const float* __restrict__ Wproj,
                             const float* __restrict__ Wemb, const float* __restrict__ bemb,
                             const float* __restrict__ Wih0, const float* __restrict__ bih0,
                             float* __restrict__ ws) {
  int idx = blockIdx.x * blockDim.x + threadIdx.x;
  if (idx < 196608) { int o = idx % G1, k = idx / G1; ws[O_HH0 + k*G1 + o] = Whh0[o*H1D + k]; return; }
  idx -= 196608;
  if (idx < 98304)  { int o = idx % G2, k = idx / G2; ws[O_IH1 + k*G2 + o] = Wih1[o*H1D + k]; return; }
  idx -= 98304;
  if (idx < 49152)  { int o = idx % G2, k = idx / G2; ws[O_HH1 + k*G2 + o] = Whh1[o*H2D + k]; return; }
  idx -= 49152;
  if (idx < 12288)  { int o = idx % G3, k = idx / G3; ws[O_IH2 + k*G3 + o] = Wih2[o*H2D + k]; return; }
  idx -= 12288;
  if (idx < 3072)   { int o = idx % G3, k = idx / G3; ws[O_HH2 + k*G3 + o] = Whh2[o*H3D + k]; return; }
  idx -= 3072;
  if (idx < 1312)   { int o = idx % VOC, k = idx / VOC; ws[O_PROJ + k*VOC + o] = Wproj[o*H3D + k]; return; }
  idx -= 1312;
  if (idx < 31488) {
    // gi0 table: exact (f64-accumulated) x@Wih0.T + bih0 per token value.
    int o = idx % G1, v = idx / G1;
    double acc = (double)bih0[o];
    const float* wrow = Wih0 + (size_t)o * H0D;
    for (int k = 0; k < H0D; ++k)
      acc += ((double)Wemb[k*VOC + v] + (double)bemb[k]) * (double)wrow[k];
    ws[O_TAB + v*G1 + o] = (float)acc;
  }
}

__device__ __forceinline__ double sigmd(double x) { return 1.0 / (1.0 + exp(-x)); }

__global__ __launch_bounds__(NT, 2) void gru_persist(
    const float* __restrict__ latent, const int* __restrict__ tgt,
    const float* __restrict__ Winit, const float* __restrict__ binit,
    const float* __restrict__ bhh0,
    const float* __restrict__ bih1, const float* __restrict__ bhh1,
    const float* __restrict__ bih2, const float* __restrict__ bhh2,
    const float* __restrict__ bproj,
    const float* __restrict__ ws, float* __restrict__ out)
{
  const int tid = threadIdx.x;
  const int r0 = blockIdx.x * RT;

  const float* wt_hh0 = ws + O_HH0;
  const float* wt_ih1 = ws + O_IH1;
  const float* wt_hh1 = ws + O_HH1;
  const float* wt_ih2 = ws + O_IH2;
  const float* wt_hh2 = ws + O_HH2;
  const float* wt_proj = ws + O_PROJ;
  const float* tab = ws + O_TAB;

  float* __restrict__ out_logits = out;
  float* __restrict__ out_pred = out + (size_t)BATCH * SEQ * VOC;

  // h states live in LDS as f64 holding exactly-f32-rounded values (bit-identical
  // math to the f32-array version, but removes every per-k v_cvt_f64_f32 on h).
  __shared__ __align__(16) double h0s[RT][H1D];   // 8 KB
  __shared__ __align__(16) double h1s[RT][H2D];   // 4 KB
  __shared__ __align__(16) double h2s[RT][H3D];   // 1 KB
  __shared__ float scA[RT][3][H1D];       // 12 KB  (stage A kh=1 partials)
  __shared__ float scBi[RT][3][H2D];      // 6 KB   (stage B gi1 g=1 partials)
  __shared__ float scBh[2][RT][3][H2D];   // 12 KB  (stage B gh1 g=2,3 partials)
  __shared__ float scC[10][3][RT][H3D];   // 15 KB  (stage C partials)
  // total 58 KB

  const int j  = tid & 255;
  const int kh = tid >> 8;
  const int jb = tid & 127;
  const int g  = tid >> 7;
  const int jc = tid & 31;
  const int sc = tid >> 5;   // 0..15
  const int wv = tid >> 6;   // wave id 0..7
  const int lane = tid & 63;

  // ---- hoist all combine biases into f64 registers (t-invariant; same values
  //      as per-step (double)load in the previous version)
  const double bA_r = (double)bhh0[j], bA_z = (double)bhh0[256 + j], bA_n = (double)bhh0[512 + j];
  const double bB_ir = (double)bih1[jb], bB_iz = (double)bih1[128 + jb], bB_in = (double)bih1[256 + jb];
  const double bB_hr = (double)bhh1[jb], bB_hz = (double)bhh1[128 + jb], bB_hn = (double)bhh1[256 + jb];
  const int jj2 = lane & 31;
  const double bC_ir = (double)bih2[jj2], bC_iz = (double)bih2[32 + jj2], bC_in = (double)bih2[64 + jj2];
  const double bC_hr = (double)bhh2[jj2], bC_hz = (double)bhh2[32 + jj2], bC_hn = (double)bhh2[64 + jj2];
  const int cpr = (lane < VOC) ? lane : 0;
  const double bPd = (double)bproj[cpr];

  // ---- init hidden states: combined = latent @ Winit.T + binit (f64 accumulate)
  for (int idx = tid; idx < RT * 416; idx += NT) {
    int r = idx / 416, jj = idx - r * 416;
    const float* lrow = latent + (size_t)(r0 + r) * LAT;
    const float* wrow = Winit + (size_t)jj * LAT;
    double acc = (double)binit[jj];
    for (int k = 0; k < LAT; ++k) acc += (double)lrow[k] * (double)wrow[k];
    float a = (float)acc;                    // keep the f32 rounding point
    if (jj < H1D) h0s[r][jj] = (double)a;
    else if (jj < H1D + H2D) h1s[r][jj - H1D] = (double)a;
    else h2s[r][jj - H1D - H2D] = (double)a;
  }
  __syncthreads();

  for (int t = 0; t < SEQ; ++t) {
    // ======== Stage A: GRU0. j = tid&255, K split in half by kh = tid>>8 ========
    {
      double aR[RT], aZ[RT], aN[RT];
      #pragma unroll
      for (int r = 0; r < RT; ++r) { aR[r] = 0.0; aZ[r] = 0.0; aN[r] = 0.0; }
      const float* __restrict__ wbase = wt_hh0 + j;
      const int k0 = kh * 128;
      for (int kb = k0; kb < k0 + 128; kb += 4) {
        double hbuf[RT][4];
        #pragma unroll
        for (int r = 0; r < RT; ++r) {
          double2 a = *(const double2*)&h0s[r][kb];
          double2 b = *(const double2*)&h0s[r][kb + 2];
          hbuf[r][0] = a.x; hbuf[r][1] = a.y; hbuf[r][2] = b.x; hbuf[r][3] = b.y;
        }
        #pragma unroll
        for (int u = 0; u < 4; ++u) {
          const float* wp = wbase + (size_t)(kb + u) * G1;
          const double wr = (double)wp[0], wz = (double)wp[256], wn = (double)wp[512];
          #pragma unroll
          for (int r = 0; r < RT; ++r) {
            const double hval = hbuf[r][u];
            aR[r] = fma(hval, wr, aR[r]);
            aZ[r] = fma(hval, wz, aZ[r]);
            aN[r] = fma(hval, wn, aN[r]);
          }
        }
      }
      if (kh == 1) {
        #pragma unroll
        for (int r = 0; r < RT; ++r) {
          scA[r][0][j] = (float)aR[r];
          scA[r][1][j] = (float)aZ[r];
          scA[r][2][j] = (float)aN[r];
        }
      }
      __syncthreads();  // B1: scA partials visible; all h0s reads done
      if (kh == 0) {
        float h0n[RT];
        #pragma unroll
        for (int r = 0; r < RT; ++r) {
          const int tok = (t == 0) ? SOS : tgt[(size_t)(r0 + r) * SEQ + t];
          const float* trow = tab + (size_t)tok * G1;
          double gR = (double)trow[j] + aR[r] + (double)scA[r][0][j] + bA_r;
          double gZ = (double)trow[256 + j] + aZ[r] + (double)scA[r][1][j] + bA_z;
          double giN = (double)trow[512 + j];
          double ghN = aN[r] + (double)scA[r][2][j] + bA_n;
          double rg = sigmd(gR);
          double zg = sigmd(gZ);
          double ng = tanh(fma(rg, ghN, giN));
          h0n[r] = (float)((1.0 - zg) * ng + zg * h0s[r][j]);
        }
        #pragma unroll
        for (int r = 0; r < RT; ++r) h0s[r][j] = (double)h0n[r];
      }
    }
    __syncthreads();  // B2: h0s new visible

    // ======== Stage B: GRU1. jb = tid&127; g = tid>>7: g0,g1 = gi1 K-halves (new h0s),
    //                                                     g2,g3 = gh1 K-halves (old h1s) ========
    {
      double bRv[RT], bZv[RT], bNv[RT];
      #pragma unroll
      for (int r = 0; r < RT; ++r) { bRv[r] = 0.0; bZv[r] = 0.0; bNv[r] = 0.0; }
      if (g < 2) {
        const float* __restrict__ wbase = wt_ih1 + jb;
        const int k0 = g * 128;
        for (int kb = k0; kb < k0 + 128; kb += 4) {
          double hbuf[RT][4];
          #pragma unroll
          for (int r = 0; r < RT; ++r) {
            double2 a = *(const double2*)&h0s[r][kb];
            double2 b = *(const double2*)&h0s[r][kb + 2];
            hbuf[r][0] = a.x; hbuf[r][1] = a.y; hbuf[r][2] = b.x; hbuf[r][3] = b.y;
          }
          #pragma unroll
          for (int u = 0; u < 4; ++u) {
            const float* wp = wbase + (size_t)(kb + u) * G2;
            const double wr = (double)wp[0], wz = (double)wp[128], wn = (double)wp[256];
            #pragma unroll
            for (int r = 0; r < RT; ++r) {
              const double hval = hbuf[r][u];
              bRv[r] = fma(hval, wr, bRv[r]);
              bZv[r] = fma(hval, wz, bZv[r]);
              bNv[r] = fma(hval, wn, bNv[r]);
            }
          }
        }
        if (g == 1) {
          #pragma unroll
          for (int r = 0; r < RT; ++r) {
            scBi[r][0][jb] = (float)bRv[r];
            scBi[r][1][jb] = (float)bZv[r];
            scBi[r][2][jb] = (float)bNv[r];
          }
        }
      } else {
        const float* __restrict__ wbase = wt_hh1 + jb;
        const int k0 = (g - 2) * 64;
        for (int kb = k0; kb < k0 + 64; kb += 4) {
          double hbuf[RT][4];
          #pragma unroll
          for (int r = 0; r < RT; ++r) {
            double2 a = *(const double2*)&h1s[r][kb];
            double2 b = *(const double2*)&h1s[r][kb + 2];
            hbuf[r][0] = a.x; hbuf[r][1] = a.y; hbuf[r][2] = b.x; hbuf[r][3] = b.y;
          }
          #pragma unroll
          for (int u = 0; u < 4; ++u) {
            const float* wp = wbase + (size_t)(kb + u) * G2;
            const double wr = (double)wp[0], wz = (double)wp[128], wn = (double)wp[256];
            #pragma unroll
            for (int r = 0; r < RT; ++r) {
              const double hval = hbuf[r][u];
              bRv[r] = fma(hval, wr, bRv[r]);
              bZv[r] = fma(hval, wz, bZv[r]);
              bNv[r] = fma(hval, wn, bNv[r]);
            }
          }
        }
        #pragma unroll
        for (int r = 0; r < RT; ++r) {
          scBh[g - 2][r][0][jb] = (float)bRv[r];
          scBh[g - 2][r][1][jb] = (float)bZv[r];
          scBh[g - 2][r][2][jb] = (float)bNv[r];
        }
      }
      __syncthreads();  // B3: partials visible; all h1s reads done
      if (g == 0) {
        float h1n[RT];
        #pragma unroll
        for (int r = 0; r < RT; ++r) {
          double giR = bRv[r] + (double)scBi[r][0][jb] + bB_ir;
          double giZ = bZv[r] + (double)scBi[r][1][jb] + bB_iz;
          double giN = bNv[r] + (double)scBi[r][2][jb] + bB_in;
          double ghR = (double)scBh[0][r][0][jb] + (double)scBh[1][r][0][jb] + bB_hr;
          double ghZ = (double)scBh[0][r][1][jb] + (double)scBh[1][r][1][jb] + bB_hz;
          double ghN = (double)scBh[0][r][2][jb] + (double)scBh[1][r][2][jb] + bB_hn;
          double rg = sigmd(giR + ghR);
          double zg = sigmd(giZ + ghZ);
          double ng = tanh(fma(rg, ghN, giN));
          h1n[r] = (float)((1.0 - zg) * ng + zg * h1s[r][jb]);
        }
        #pragma unroll
        for (int r = 0; r < RT; ++r) h1s[r][jb] = (double)h1n[r];
      }
    }
    __syncthreads();  // B4: h1s new visible

    // ======== Stage C: GRU2. jc = tid&31; sc = tid>>5: sc0..7 = gi2 K-slices of 16 (new h1s),
    //                                                    sc8,9 = gh2 K-slices of 16 (old h2s) ========
    {
      double cR[RT], cZ[RT], cN[RT];
      #pragma unroll
      for (int r = 0; r < RT; ++r) { cR[r] = 0.0; cZ[r] = 0.0; cN[r] = 0.0; }
      if (sc < 8) {
        for (int kk = 0; kk < 16; ++kk) {
          int k = sc * 16 + kk;
          const float* wp = wt_ih2 + (size_t)k * G3;
          const double wr = (double)wp[jc], wz = (double)wp[32 + jc], wn = (double)wp[64 + jc];
          #pragma unroll
          for (int r = 0; r < RT; ++r) {
            const double hval = h1s[r][k];
            cR[r] = fma(hval, wr, cR[r]);
            cZ[r] = fma(hval, wz, cZ[r]);
            cN[r] = fma(hval, wn, cN[r]);
          }
        }
      } else if (sc < 10) {
        for (int kk = 0; kk < 16; ++kk) {
          int k = (sc - 8) * 16 + kk;
          const float* wp = wt_hh2 + (size_t)k * G3;
          const double wr = (double)wp[jc], wz = (double)wp[32 + jc], wn = (double)wp[64 + jc];
          #pragma unroll
          for (int r = 0; r < RT; ++r) {
            const double hval = h2s[r][k];
            cR[r] = fma(hval, wr, cR[r]);
            cZ[r] = fma(hval, wz, cZ[r]);
            cN[r] = fma(hval, wn, cN[r]);
          }
        }
      }
      if (sc < 10) {
        #pragma unroll
        for (int r = 0; r < RT; ++r) {
          scC[sc][0][r][jc] = (float)cR[r];
          scC[sc][1][r][jc] = (float)cZ[r];
          scC[sc][2][r][jc] = (float)cN[r];
        }
      }
    }
    __syncthreads();  // B5: scC partials visible; all h2s(old) reads done

    // ======== Stage C combine + projection + argmax, fused per-row into waves 0-3.
    //          Waves 4-7 fall through immediately into stage A of step t+1 —
    //          their scA(t+1) writes only land after B1(t+1), whose readers of
    //          scA(t)/h0s(t) all completed before B2(t)/B5(t). ========
    if (wv < 4) {
      const int r = wv;
      float h2f = 0.0f;
      if (lane < 32) {
        const int jj = lane;
        double giR = bC_ir, giZ = bC_iz, giN = bC_in;
        #pragma unroll
        for (int s = 0; s < 8; ++s) {
          giR += (double)scC[s][0][r][jj];
          giZ += (double)scC[s][1][r][jj];
          giN += (double)scC[s][2][r][jj];
        }
        double ghR = (double)scC[8][0][r][jj] + (double)scC[9][0][r][jj] + bC_hr;
        double ghZ = (double)scC[8][1][r][jj] + (double)scC[9][1][r][jj] + bC_hz;
        double ghN = (double)scC[8][2][r][jj] + (double)scC[9][2][r][jj] + bC_hn;
        double rg = sigmd(giR + ghR);
        double zg = sigmd(giZ + ghZ);
        double ng = tanh(fma(rg, ghN, giN));
        h2f = (float)((1.0 - zg) * ng + zg * h2s[r][jj]);
        h2s[r][jj] = (double)h2f;   // for next step's gh2 (reader passes >=4 barriers first)
      }
      // projection: lane c computes logit c; h2 broadcast from lanes 0..31 registers
      double acc = bPd;
      #pragma unroll
      for (int k = 0; k < H3D; ++k) {
        const float hk = __shfl(h2f, k);
        acc = fma((double)hk, (double)wt_proj[k * VOC + cpr], acc);
      }
      const float accf = (float)acc;
      if (lane < VOC)
        out_logits[((size_t)(r0 + r) * SEQ + t) * VOC + lane] = accf;
      // wave-wide argmax, first-max (lowest index) tie-break to match jnp.argmax
      float val = (lane < VOC) ? accf : -3.402823466e38f;
      int idx = lane;
      #pragma unroll
      for (int off = 32; off > 0; off >>= 1) {
        const float ov = __shfl_xor(val, off);
        const int   oi = __shfl_xor(idx, off);
        if (ov > val || (ov == val && oi < idx)) { val = ov; idx = oi; }
      }
      if (lane == 0)
        out_pred[(size_t)(r0 + r) * SEQ + t] = (float)idx;
    }
    // no barrier here: B1(t+1) provides the ordering for all cross-wave hazards.
    // Hazard audit (per buffer, writer(t+1) vs reader(t)):
    //  h0s: W after B1(t+1) / R before B1(t+1) and before B2(t) — OK
    //  scA: W before B1(t+1) by waves 4-7 / R before B2(t) — >=3 barriers apart — OK
    //  h1s,scBi,scBh: W after B3(t+1) / R before B4(t) — OK
    //  h2s: W after B5(t+1) / R (gh2) before B5(t+1)... wave4 reads after B4(t+1) of
    //       values written before B1(t+1) — OK
    //  scC: W at stage C(t+1) after B4(t+1) / R right after B5(t) — OK
  }
}

extern "C" void kernel_launch(void* const* d_in, const int* in_sizes, int n_in,
                              void* d_out, int out_size, void* d_ws, size_t ws_size,
                              hipStream_t stream) {
  const float* latent  = (const float*)d_in[0];
  const int*   tgt     = (const int*)d_in[1];
  const float* Wemb    = (const float*)d_in[2];
  const float* bemb    = (const float*)d_in[3];
  const float* Winit   = (const float*)d_in[4];
  const float* binit   = (const float*)d_in[5];
  const float* Wih0    = (const float*)d_in[6];
  const float* Whh0    = (const float*)d_in[7];
  const float* bih0    = (const float*)d_in[8];
  const float* bhh0    = (const float*)d_in[9];
  const float* Wih1    = (const float*)d_in[10];
  const float* Whh1    = (const float*)d_in[11];
  const float* bih1    = (const float*)d_in[12];
  const float* bhh1    = (const float*)d_in[13];
  const float* Wih2    = (const float*)d_in[14];
  const float* Whh2    = (const float*)d_in[15];
  const float* bih2    = (const float*)d_in[16];
  const float* bhh2    = (const float*)d_in[17];
  const float* Wproj   = (const float*)d_in[18];
  const float* bproj   = (const float*)d_in[19];

  float* ws = (float*)d_ws;
  float* out = (float*)d_out;

  int setup_threads = WS_FLOATS;
  int setup_blocks = (setup_threads + 255) / 256;
  setup_kernel<<<setup_blocks, 256, 0, stream>>>(Whh0, Wih1, Whh1, Wih2, Whh2, Wproj,
                                                Wemb, bemb, Wih0, bih0, ws);

  gru_persist<<<BATCH / RT, NT, 0, stream>>>(latent, tgt, Winit, binit,
                                             bhh0, bih1, bhh1, bih2, bhh2, bproj,
                                             ws, out);
}

// Round 2
// 8719.935 us; speedup vs baseline: 1.0875x; 1.0875x over previous
//
#include <hip/hip_runtime.h>
#include <hip/hip_bf16.h>

// Problem constants
#define BATCH 1024
#define SEQ   350
#define LAT   512
#define VOC   41
#define H0D   512
#define H1D   256
#define H2D   128
#define H3D   32
#define G1    768   // 3*H1D
#define G2    384   // 3*H2D
#define G3    96    // 3*H3D
#define SOS   1

// ws layout (floats) — UNCHANGED
#define O_HH0   0         // wt_hh0 [256][768]
#define O_IH1   196608    // wt_ih1 [256][384]
#define O_HH1   294912    // wt_hh1 [128][384]
#define O_IH2   344064    // wt_ih2 [128][96]
#define O_HH2   356352    // wt_hh2 [32][96]
#define O_PROJ  359424    // wt_proj [32][41]
#define O_TAB   360736    // gi0 table [41][768]
#define WS_FLOATS 392224

#define RT 4    // batch rows per block
#define NT 512  // threads per block (8 waves)

__global__ void setup_kernel(const float* __restrict__ Whh0, const float* __restrict__ Wih1,
                             const float* __restrict__ Whh1, const float* __restrict__ Wih2,
                             const float* __restrict__ Whh2, const float* __restrict__ Wproj,
                             const float* __restrict__ Wemb, const float* __restrict__ bemb,
                             const float* __restrict__ Wih0, const float* __restrict__ bih0,
                             float* __restrict__ ws) {
  int idx = blockIdx.x * blockDim.x + threadIdx.x;
  if (idx < 196608) { int o = idx % G1, k = idx / G1; ws[O_HH0 + k*G1 + o] = Whh0[o*H1D + k]; return; }
  idx -= 196608;
  if (idx < 98304)  { int o = idx % G2, k = idx / G2; ws[O_IH1 + k*G2 + o] = Wih1[o*H1D + k]; return; }
  idx -= 98304;
  if (idx < 49152)  { int o = idx % G2, k = idx / G2; ws[O_HH1 + k*G2 + o] = Whh1[o*H2D + k]; return; }
  idx -= 49152;
  if (idx < 12288)  { int o = idx % G3, k = idx / G3; ws[O_IH2 + k*G3 + o] = Wih2[o*H2D + k]; return; }
  idx -= 12288;
  if (idx < 3072)   { int o = idx % G3, k = idx / G3; ws[O_HH2 + k*G3 + o] = Whh2[o*H3D + k]; return; }
  idx -= 3072;
  if (idx < 1312)   { int o = idx % VOC, k = idx / VOC; ws[O_PROJ + k*VOC + o] = Wproj[o*H3D + k]; return; }
  idx -= 1312;
  if (idx < 31488) {
    // gi0 table: exact (f64-accumulated) x@Wih0.T + bih0 per token value.
    int o = idx % G1, v = idx / G1;
    double acc = (double)bih0[o];
    const float* wrow = Wih0 + (size_t)o * H0D;
    for (int k = 0; k < H0D; ++k)
      acc += ((double)Wemb[k*VOC + v] + (double)bemb[k]) * (double)wrow[k];
    ws[O_TAB + v*G1 + o] = (float)acc;
  }
}

__device__ __forceinline__ double sigmd(double x) { return 1.0 / (1.0 + exp(-x)); }

__global__ __launch_bounds__(NT, 2) void gru_persist(
    const float* __restrict__ latent, const int* __restrict__ tgt,
    const float* __restrict__ Winit, const float* __restrict__ binit,
    const float* __restrict__ bhh0,
    const float* __restrict__ bih1, const float* __restrict__ bhh1,
    const float* __restrict__ bih2, const float* __restrict__ bhh2,
    const float* __restrict__ bproj,
    const float* __restrict__ ws, float* __restrict__ out)
{
  const int tid = threadIdx.x;
  const int r0 = blockIdx.x * RT;

  const float* wt_hh0 = ws + O_HH0;
  const float* wt_ih1 = ws + O_IH1;
  const float* wt_hh1 = ws + O_HH1;
  const float* wt_ih2 = ws + O_IH2;
  const float* wt_hh2 = ws + O_HH2;
  const float* wt_proj = ws + O_PROJ;
  const float* tab = ws + O_TAB;

  float* __restrict__ out_logits = out;
  float* __restrict__ out_pred = out + (size_t)BATCH * SEQ * VOC;

  // f32 K-loops this round: h states back to f32 (float4-readable), weights
  // feed v_fmac_f32 directly with zero converts. Combine/transcendentals stay f64.
  __shared__ __align__(16) float h0s[RT][H1D];   // 4 KB
  __shared__ __align__(16) float h1s[RT][H2D];   // 2 KB
  __shared__ __align__(16) float h2s[RT][H3D];   // 0.5 KB
  __shared__ float scA[RT][3][H1D];       // 12 KB  (stage A kh=1 partials)
  __shared__ float scBi[RT][3][H2D];      // 6 KB   (stage B gi1 g=1 partials)
  __shared__ float scBh[2][RT][3][H2D];   // 12 KB  (stage B gh1 g=2,3 partials)
  __shared__ float scC[10][3][RT][H3D];   // 15 KB  (stage C partials)
  // total ~52 KB

  const int j  = tid & 255;
  const int kh = tid >> 8;
  const int jb = tid & 127;
  const int g  = tid >> 7;
  const int jc = tid & 31;
  const int sc = tid >> 5;   // 0..15
  const int wv = tid >> 6;   // wave id 0..7
  const int lane = tid & 63;

  // ---- hoist all combine biases into f64 registers (t-invariant)
  const double bA_r = (double)bhh0[j], bA_z = (double)bhh0[256 + j], bA_n = (double)bhh0[512 + j];
  const double bB_ir = (double)bih1[jb], bB_iz = (double)bih1[128 + jb], bB_in = (double)bih1[256 + jb];
  const double bB_hr = (double)bhh1[jb], bB_hz = (double)bhh1[128 + jb], bB_hn = (double)bhh1[256 + jb];
  const int jj2 = lane & 31;
  const double bC_ir = (double)bih2[jj2], bC_iz = (double)bih2[32 + jj2], bC_in = (double)bih2[64 + jj2];
  const double bC_hr = (double)bhh2[jj2], bC_hz = (double)bhh2[32 + jj2], bC_hn = (double)bhh2[64 + jj2];
  const int cpr = (lane < VOC) ? lane : 0;
  const double bPd = (double)bproj[cpr];

  // ---- init hidden states: combined = latent @ Winit.T + binit (f64 accumulate, one-time)
  for (int idx = tid; idx < RT * 416; idx += NT) {
    int r = idx / 416, jj = idx - r * 416;
    const float* lrow = latent + (size_t)(r0 + r) * LAT;
    const float* wrow = Winit + (size_t)jj * LAT;
    double acc = (double)binit[jj];
    for (int k = 0; k < LAT; ++k) acc += (double)lrow[k] * (double)wrow[k];
    float a = (float)acc;
    if (jj < H1D) h0s[r][jj] = a;
    else if (jj < H1D + H2D) h1s[r][jj - H1D] = a;
    else h2s[r][jj - H1D - H2D] = a;
  }
  __syncthreads();

  for (int t = 0; t < SEQ; ++t) {
    // ======== Stage A: GRU0. j = tid&255, K split in half by kh = tid>>8 ========
    {
      float aR[RT], aZ[RT], aN[RT];
      #pragma unroll
      for (int r = 0; r < RT; ++r) { aR[r] = 0.0f; aZ[r] = 0.0f; aN[r] = 0.0f; }
      const float* __restrict__ wbase = wt_hh0 + j;
      const int k0 = kh * 128;
      for (int kb = k0; kb < k0 + 128; kb += 4) {
        float4 hv[RT];
        #pragma unroll
        for (int r = 0; r < RT; ++r) hv[r] = *(const float4*)&h0s[r][kb];
        #pragma unroll
        for (int u = 0; u < 4; ++u) {
          const float* wp = wbase + (size_t)(kb + u) * G1;
          const float wr = wp[0], wz = wp[256], wn = wp[512];
          #pragma unroll
          for (int r = 0; r < RT; ++r) {
            const float hval = ((const float*)&hv[r])[u];
            aR[r] = fmaf(hval, wr, aR[r]);
            aZ[r] = fmaf(hval, wz, aZ[r]);
            aN[r] = fmaf(hval, wn, aN[r]);
          }
        }
      }
      if (kh == 1) {
        #pragma unroll
        for (int r = 0; r < RT; ++r) {
          scA[r][0][j] = aR[r];
          scA[r][1][j] = aZ[r];
          scA[r][2][j] = aN[r];
        }
      }
      __syncthreads();  // B1: scA partials visible; all h0s reads done
      if (kh == 0) {
        float h0n[RT];
        #pragma unroll
        for (int r = 0; r < RT; ++r) {
          const int tok = (t == 0) ? SOS : tgt[(size_t)(r0 + r) * SEQ + t];
          const float* trow = tab + (size_t)tok * G1;
          double gR = (double)trow[j] + (double)aR[r] + (double)scA[r][0][j] + bA_r;
          double gZ = (double)trow[256 + j] + (double)aZ[r] + (double)scA[r][1][j] + bA_z;
          double giN = (double)trow[512 + j];
          double ghN = (double)aN[r] + (double)scA[r][2][j] + bA_n;
          double rg = sigmd(gR);
          double zg = sigmd(gZ);
          double ng = tanh(fma(rg, ghN, giN));
          h0n[r] = (float)((1.0 - zg) * ng + zg * (double)h0s[r][j]);
        }
        #pragma unroll
        for (int r = 0; r < RT; ++r) h0s[r][j] = h0n[r];
      }
    }
    __syncthreads();  // B2: h0s new visible

    // ======== Stage B: GRU1. jb = tid&127; g = tid>>7: g0,g1 = gi1 K-halves (new h0s),
    //                                                     g2,g3 = gh1 K-halves (old h1s) ========
    {
      float bRv[RT], bZv[RT], bNv[RT];
      #pragma unroll
      for (int r = 0; r < RT; ++r) { bRv[r] = 0.0f; bZv[r] = 0.0f; bNv[r] = 0.0f; }
      if (g < 2) {
        const float* __restrict__ wbase = wt_ih1 + jb;
        const int k0 = g * 128;
        for (int kb = k0; kb < k0 + 128; kb += 4) {
          float4 hv[RT];
          #pragma unroll
          for (int r = 0; r < RT; ++r) hv[r] = *(const float4*)&h0s[r][kb];
          #pragma unroll
          for (int u = 0; u < 4; ++u) {
            const float* wp = wbase + (size_t)(kb + u) * G2;
            const float wr = wp[0], wz = wp[128], wn = wp[256];
            #pragma unroll
            for (int r = 0; r < RT; ++r) {
              const float hval = ((const float*)&hv[r])[u];
              bRv[r] = fmaf(hval, wr, bRv[r]);
              bZv[r] = fmaf(hval, wz, bZv[r]);
              bNv[r] = fmaf(hval, wn, bNv[r]);
            }
          }
        }
        if (g == 1) {
          #pragma unroll
          for (int r = 0; r < RT; ++r) {
            scBi[r][0][jb] = bRv[r];
            scBi[r][1][jb] = bZv[r];
            scBi[r][2][jb] = bNv[r];
          }
        }
      } else {
        const float* __restrict__ wbase = wt_hh1 + jb;
        const int k0 = (g - 2) * 64;
        for (int kb = k0; kb < k0 + 64; kb += 4) {
          float4 hv[RT];
          #pragma unroll
          for (int r = 0; r < RT; ++r) hv[r] = *(const float4*)&h1s[r][kb];
          #pragma unroll
          for (int u = 0; u < 4; ++u) {
            const float* wp = wbase + (size_t)(kb + u) * G2;
            const float wr = wp[0], wz = wp[128], wn = wp[256];
            #pragma unroll
            for (int r = 0; r < RT; ++r) {
              const float hval = ((const float*)&hv[r])[u];
              bRv[r] = fmaf(hval, wr, bRv[r]);
              bZv[r] = fmaf(hval, wz, bZv[r]);
              bNv[r] = fmaf(hval, wn, bNv[r]);
            }
          }
        }
        #pragma unroll
        for (int r = 0; r < RT; ++r) {
          scBh[g - 2][r][0][jb] = bRv[r];
          scBh[g - 2][r][1][jb] = bZv[r];
          scBh[g - 2][r][2][jb] = bNv[r];
        }
      }
      __syncthreads();  // B3: partials visible; all h1s reads done
      if (g == 0) {
        float h1n[RT];
        #pragma unroll
        for (int r = 0; r < RT; ++r) {
          double giR = (double)bRv[r] + (double)scBi[r][0][jb] + bB_ir;
          double giZ = (double)bZv[r] + (double)scBi[r][1][jb] + bB_iz;
          double giN = (double)bNv[r] + (double)scBi[r][2][jb] + bB_in;
          double ghR = (double)scBh[0][r][0][jb] + (double)scBh[1][r][0][jb] + bB_hr;
          double ghZ = (double)scBh[0][r][1][jb] + (double)scBh[1][r][1][jb] + bB_hz;
          double ghN = (double)scBh[0][r][2][jb] + (double)scBh[1][r][2][jb] + bB_hn;
          double rg = sigmd(giR + ghR);
          double zg = sigmd(giZ + ghZ);
          double ng = tanh(fma(rg, ghN, giN));
          h1n[r] = (float)((1.0 - zg) * ng + zg * (double)h1s[r][jb]);
        }
        #pragma unroll
        for (int r = 0; r < RT; ++r) h1s[r][jb] = h1n[r];
      }
    }
    __syncthreads();  // B4: h1s new visible

    // ======== Stage C: GRU2. jc = tid&31; sc = tid>>5: sc0..7 = gi2 K-slices of 16 (new h1s),
    //                                                    sc8,9 = gh2 K-slices of 16 (old h2s) ========
    {
      float cR[RT], cZ[RT], cN[RT];
      #pragma unroll
      for (int r = 0; r < RT; ++r) { cR[r] = 0.0f; cZ[r] = 0.0f; cN[r] = 0.0f; }
      if (sc < 8) {
        for (int kk = 0; kk < 16; ++kk) {
          int k = sc * 16 + kk;
          const float* wp = wt_ih2 + (size_t)k * G3;
          const float wr = wp[jc], wz = wp[32 + jc], wn = wp[64 + jc];
          #pragma unroll
          for (int r = 0; r < RT; ++r) {
            const float hval = h1s[r][k];
            cR[r] = fmaf(hval, wr, cR[r]);
            cZ[r] = fmaf(hval, wz, cZ[r]);
            cN[r] = fmaf(hval, wn, cN[r]);
          }
        }
      } else if (sc < 10) {
        for (int kk = 0; kk < 16; ++kk) {
          int k = (sc - 8) * 16 + kk;
          const float* wp = wt_hh2 + (size_t)k * G3;
          const float wr = wp[jc], wz = wp[32 + jc], wn = wp[64 + jc];
          #pragma unroll
          for (int r = 0; r < RT; ++r) {
            const float hval = h2s[r][k];
            cR[r] = fmaf(hval, wr, cR[r]);
            cZ[r] = fmaf(hval, wz, cZ[r]);
            cN[r] = fmaf(hval, wn, cN[r]);
          }
        }
      }
      if (sc < 10) {
        #pragma unroll
        for (int r = 0; r < RT; ++r) {
          scC[sc][0][r][jc] = cR[r];
          scC[sc][1][r][jc] = cZ[r];
          scC[sc][2][r][jc] = cN[r];
        }
      }
    }
    __syncthreads();  // B5: scC partials visible; all h2s(old) reads done

    // ======== Stage C combine + projection + argmax, fused per-row into waves 0-3.
    //          Waves 4-7 fall through immediately into stage A of step t+1. ========
    if (wv < 4) {
      const int r = wv;
      float h2f = 0.0f;
      if (lane < 32) {
        const int jj = lane;
        double giR = bC_ir, giZ = bC_iz, giN = bC_in;
        #pragma unroll
        for (int s = 0; s < 8; ++s) {
          giR += (double)scC[s][0][r][jj];
          giZ += (double)scC[s][1][r][jj];
          giN += (double)scC[s][2][r][jj];
        }
        double ghR = (double)scC[8][0][r][jj] + (double)scC[9][0][r][jj] + bC_hr;
        double ghZ = (double)scC[8][1][r][jj] + (double)scC[9][1][r][jj] + bC_hz;
        double ghN = (double)scC[8][2][r][jj] + (double)scC[9][2][r][jj] + bC_hn;
        double rg = sigmd(giR + ghR);
        double zg = sigmd(giZ + ghZ);
        double ng = tanh(fma(rg, ghN, giN));
        h2f = (float)((1.0 - zg) * ng + zg * (double)h2s[r][jj]);
        h2s[r][jj] = h2f;   // for next step's gh2 (reader passes >=4 barriers first)
      }
      // projection: lane c computes logit c; h2 broadcast from lanes 0..31 registers
      double acc = bPd;
      #pragma unroll
      for (int k = 0; k < H3D; ++k) {
        const float hk = __shfl(h2f, k);
        acc = fma((double)hk, (double)wt_proj[k * VOC + cpr], acc);
      }
      const float accf = (float)acc;
      if (lane < VOC)
        out_logits[((size_t)(r0 + r) * SEQ + t) * VOC + lane] = accf;
      // wave-wide argmax, first-max (lowest index) tie-break to match jnp.argmax
      float val = (lane < VOC) ? accf : -3.402823466e38f;
      int idx = lane;
      #pragma unroll
      for (int off = 32; off > 0; off >>= 1) {
        const float ov = __shfl_xor(val, off);
        const int   oi = __shfl_xor(idx, off);
        if (ov > val || (ov == val && oi < idx)) { val = ov; idx = oi; }
      }
      if (lane == 0)
        out_pred[(size_t)(r0 + r) * SEQ + t] = (float)idx;
    }
    // no barrier here: B1(t+1) provides the ordering for all cross-wave hazards.
    // Hazard audit identical to previous (passing) version:
    //  h0s: W after B1(t+1) / R before B1(t+1) and before B2(t) — OK
    //  scA: W before B1(t+1) by waves 4-7 / R before B2(t) — OK
    //  h1s,scBi,scBh: W after B3(t+1) / R before B4(t) — OK
    //  h2s: W by waves 0-3 before stage A(t+1) FMA work; readers (sc8,9) of old
    //       value completed before B5(t); next readers after B4(t+1) — OK
    //  scC: W at stage C(t+1) after B4(t+1) / R right after B5(t) — OK
  }
}

extern "C" void kernel_launch(void* const* d_in, const int* in_sizes, int n_in,
                              void* d_out, int out_size, void* d_ws, size_t ws_size,
                              hipStream_t stream) {
  const float* latent  = (const float*)d_in[0];
  const int*   tgt     = (const int*)d_in[1];
  const float* Wemb    = (const float*)d_in[2];
  const float* bemb    = (const float*)d_in[3];
  const float* Winit   = (const float*)d_in[4];
  const float* binit   = (const float*)d_in[5];
  const float* Wih0    = (const float*)d_in[6];
  const float* Whh0    = (const float*)d_in[7];
  const float* bih0    = (const float*)d_in[8];
  const float* bhh0    = (const float*)d_in[9];
  const float* Wih1    = (const float*)d_in[10];
  const float* Whh1    = (const float*)d_in[11];
  const float* bih1    = (const float*)d_in[12];
  const float* bhh1    = (const float*)d_in[13];
  const float* Wih2    = (const float*)d_in[14];
  const float* Whh2    = (const float*)d_in[15];
  const float* bih2    = (const float*)d_in[16];
  const float* bhh2    = (const float*)d_in[17];
  const float* Wproj   = (const float*)d_in[18];
  const float* bproj   = (const float*)d_in[19];

  float* ws = (float*)d_ws;
  float* out = (float*)d_out;

  int setup_threads = WS_FLOATS;
  int setup_blocks = (setup_threads + 255) / 256;
  setup_kernel<<<setup_blocks, 256, 0, stream>>>(Whh0, Wih1, Whh1, Wih2, Whh2, Wproj,
                                                Wemb, bemb, Wih0, bih0, ws);

  gru_persist<<<BATCH / RT, NT, 0, stream>>>(latent, tgt, Winit, binit,
                                             bhh0, bih1, bhh1, bih2, bhh2, bproj,
                                             ws, out);
}